// Round 12
// baseline (492.256 us; speedup 1.0000x reference)
//
#include <hip/hip_runtime.h>
#include <hip/hip_cooperative_groups.h>
#include <hip/hip_bf16.h>
#include <math.h>

namespace cg = cooperative_groups;

#define IMG 128
#define PATCH 16
#define L 64
#define D 256
#define DIN 512
#define DH 64
#define H 8
#define NSTATE 64
#define DCONV 4
#define DEPTH 2
#define NCLS 1000
#define BATCH 16
#define DINPROJ 1160   // 2*DIN + 2*N + H
#define CDIM 640       // DIN + 2*N
#define EPS 1e-6f

typedef __attribute__((ext_vector_type(8))) short short8;
typedef __attribute__((ext_vector_type(4))) float f32x4;
typedef __attribute__((ext_vector_type(4))) unsigned short us4;
typedef unsigned short ushort_t;

__device__ __forceinline__ int snake_tok(int s){
    int r = s >> 3, c = s & 7;
    return (r & 1) ? (r * 8 + (7 - c)) : (r * 8 + c);
}
__device__ __forceinline__ float silu_f(float x){ return x / (1.f + expf(-x)); }
__device__ __forceinline__ float softplus_f(float x){ return x > 20.f ? x : log1pf(expf(x)); }
__device__ __forceinline__ ushort_t f2b(float f){
    __hip_bfloat16 h = __float2bfloat16(f);
    return *(ushort_t*)&h;
}

struct MegaP {
    const float *x, *patch_w, *patch_b, *pos, *norms_w, *final_w, *head_w, *head_b;
    const float *Win[2], *cw[2], *cb[2], *dtb[2], *Alog[2], *Dp[2], *gn[2], *Wout[2];
    float *t, *tm8;
    float *zb[2], *xy[2], *bcb[2], *dts[2], *cums[2], *ssq[2];
    float *partP, *partO;
    ushort_t *win_bf, *wout_bf;
    float *out;
};

// ---------------- phase: weight transpose+convert (1696 tile tasks)
__device__ void ph_wconv(int task, int tid, unsigned char* SM, const MegaP& p){
    float (*sm)[33] = (float(*)[33])SM;                         // 4224 B
    const float* src; ushort_t* dst; int R, C, ctiles, tile;
    if (task < 1184){
        int z = task / 296; tile = task - z * 296;              // 37*8 tiles
        src = p.Win[z & 1] + (size_t)(z >> 1) * D * DINPROJ;
        dst = p.win_bf + (size_t)z * 296960;
        R = D; C = DINPROJ; ctiles = 37;
    } else {
        int k = task - 1184;
        int z = k >> 7; tile = k & 127;                         // 8*16 tiles
        src = p.Wout[z & 1] + (size_t)(z >> 1) * DIN * D;
        dst = p.wout_bf + (size_t)z * 131072;
        R = DIN; C = D; ctiles = 8;
    }
    int cx = tile % ctiles, ry = tile / ctiles;
    int c0 = cx * 32, r0 = ry * 32;
    int tx = tid & 31, ty = tid >> 5;
    #pragma unroll
    for (int k = 0; k < 4; ++k){
        int r = r0 + ty + 8 * k, c = c0 + tx;
        sm[ty + 8 * k][tx] = (c < C) ? src[(size_t)r * C + c] : 0.f;
    }
    __syncthreads();
    #pragma unroll
    for (int k = 0; k < 4; ++k){
        int dr = c0 + ty + 8 * k, dc = r0 + tx;
        if (dr < C) dst[(size_t)dr * R + dc] = f2b(sm[tx][ty + 8 * k]);
    }
}

// ---------------- phase: patch GEMM split-K=8 (512 tasks)
__device__ void ph_patch(int task, int tid, unsigned char* SM, const MegaP& p){
    ushort_t (*As)[64][40] = (ushort_t(*)[64][40])SM;           // 10240
    ushort_t (*Bs)[64][40] = (ushort_t(*)[64][40])(SM + 10240); // 10240
    const int xi = task & 3, b = (task >> 2) & 15, split = task >> 6;
    const int n0 = xi * 64;
    const int kbase = split * 96;
    const int lrow = tid >> 2, lc8 = (tid & 3) * 8;
    const int tok = snake_tok(lrow), gy = tok >> 3, gx = tok & 7;
    const float* xb = p.x + (size_t)b * 3 * IMG * IMG;
    const int wave = tid >> 6, lane = tid & 63;
    const int wm = (wave >> 1) * 32, wn = (wave & 1) * 32;
    const int fro = lane & 15, fk = (lane >> 4) * 8;

    f32x4 acc[2][2];
    #pragma unroll
    for (int i = 0; i < 2; ++i)
        #pragma unroll
        for (int j = 0; j < 2; ++j) acc[i][j] = (f32x4){0.f,0.f,0.f,0.f};

    short8 areg, breg;
    auto gload = [&](int kk){
        int k = kk + lc8;
        int c = k >> 8, rem = k & 255, py = rem >> 4, px = rem & 15;
        const float* srcA = xb + ((size_t)c * IMG + gy * PATCH + py) * IMG + gx * PATCH + px;
        float4 a0 = *(const float4*)(srcA);
        float4 a1 = *(const float4*)(srcA + 4);
        ushort_t ta[8] = {f2b(a0.x),f2b(a0.y),f2b(a0.z),f2b(a0.w),
                          f2b(a1.x),f2b(a1.y),f2b(a1.z),f2b(a1.w)};
        areg = *(short8*)ta;
        const float* srcB = p.patch_w + (size_t)(n0 + lrow) * 768 + kk + lc8;
        float4 b0 = *(const float4*)(srcB);
        float4 b1 = *(const float4*)(srcB + 4);
        ushort_t tb[8] = {f2b(b0.x),f2b(b0.y),f2b(b0.z),f2b(b0.w),
                          f2b(b1.x),f2b(b1.y),f2b(b1.z),f2b(b1.w)};
        breg = *(short8*)tb;
    };
    auto sstore = [&](int buf){
        *(short8*)&As[buf][lrow][lc8] = areg;
        *(short8*)&Bs[buf][lrow][lc8] = breg;
    };

    const int nk = 3;
    gload(kbase); sstore(0);
    __syncthreads();
    for (int kt = 0; kt < nk; ++kt){
        const int buf = kt & 1;
        if (kt + 1 < nk) gload(kbase + (kt + 1) * 32);
        short8 af[2], bfr[2];
        af[0]  = *(const short8*)&As[buf][wm + fro][fk];
        af[1]  = *(const short8*)&As[buf][wm + 16 + fro][fk];
        bfr[0] = *(const short8*)&Bs[buf][wn + fro][fk];
        bfr[1] = *(const short8*)&Bs[buf][wn + 16 + fro][fk];
        #pragma unroll
        for (int i = 0; i < 2; ++i)
            #pragma unroll
            for (int j = 0; j < 2; ++j)
                acc[i][j] = __builtin_amdgcn_mfma_f32_16x16x32_bf16(af[i], bfr[j], acc[i][j], 0, 0, 0);
        if (kt + 1 < nk){ sstore(buf ^ 1); __syncthreads(); }
    }
    float* Cp = p.partP + (size_t)split * (BATCH * L * D);
    #pragma unroll
    for (int i = 0; i < 2; ++i){
        #pragma unroll
        for (int j = 0; j < 2; ++j){
            int col = n0 + wn + j * 16 + (lane & 15);
            #pragma unroll
            for (int r = 0; r < 4; ++r){
                int srow = wm + i * 16 + (lane >> 4) * 4 + r;
                Cp[(size_t)(b * 64 + srow) * D + col] = acc[i][j][r];
            }
        }
    }
}

// ---------------- phase: patch reduce (1024 tasks)
__device__ void ph_patchred(int task, int tid, const MegaP& p){
    int i = task * 256 + tid;
    int d = i & (D - 1), s = (i >> 8) & (L - 1);
    float v = 0.f;
    #pragma unroll
    for (int r = 0; r < 8; ++r) v += p.partP[i + r * (BATCH * L * D)];
    p.t[i] = v + p.patch_b[d] + p.pos[snake_tok(s) * D + d];
}

// ---------------- phase: in-proj GEMM + rmsnorm prologue + conv/dt epilogue (608 tasks)
__device__ void ph_gemm_in(int task, int tid, unsigned char* SM, const MegaP& p, int layer){
    ushort_t (*As)[264]    = (ushort_t(*)[264])SM;              // 33792
    ushort_t (*Bs)[64][40] = (ushort_t(*)[64][40])(SM + 33792); // 10240 (K-loop)
    float (*Ctile)[68]     = (float(*)[68])(SM + 33792);        // 17408 (aliases Bs, post-loop)

    const int xi  = task % 19;
    const int b   = (task / 19) & 15;
    const int dir = task / 304;
    const int n0 = xi * 64, m0 = b * 64;
    const ushort_t* Bw = p.win_bf + (size_t)(2 * layer + dir) * 296960;
    const float* nw = p.norms_w + layer * D;

    const int arow = tid >> 2;
    const int wave = tid >> 6, lane = tid & 63;
    const int wm = (wave >> 1) * 32, wn = (wave & 1) * 32;
    const int fro = lane & 15, fk = (lane >> 4) * 8;

    {   // rmsnorm prologue -> As bf16
        const float* src = p.t + (size_t)(m0 + arow) * D;
        float ss = 0.f;
        #pragma unroll
        for (int i = 0; i < 16; ++i){
            int c = (tid & 3) * 4 + i * 16;
            float4 v = *(const float4*)(src + c);
            ss += v.x*v.x + v.y*v.y + v.z*v.z + v.w*v.w;
        }
        ss += __shfl_xor(ss, 1);
        ss += __shfl_xor(ss, 2);
        float sc = rsqrtf(ss * (1.f / (float)D) + EPS);
        #pragma unroll
        for (int i = 0; i < 16; ++i){
            int c = (tid & 3) * 4 + i * 16;
            float4 v = *(const float4*)(src + c);
            float4 w = *(const float4*)(nw + c);
            us4 o = {f2b(v.x*sc*w.x), f2b(v.y*sc*w.y), f2b(v.z*sc*w.z), f2b(v.w*sc*w.w)};
            *(us4*)&As[arow][c] = o;
        }
    }
    const int lrow = tid >> 2, lc8 = (tid & 3) * 8;
    float4 breg;
    auto gloadB = [&](int kk){
        int gn = n0 + lrow;
        if (gn < DINPROJ) breg = *(const float4*)(Bw + (size_t)gn * D + kk + lc8);
        else breg = make_float4(0.f,0.f,0.f,0.f);
    };
    auto sstoreB = [&](int buf){ *(float4*)&Bs[buf][lrow][lc8] = breg; };

    f32x4 acc[2][2];
    #pragma unroll
    for (int i = 0; i < 2; ++i)
        #pragma unroll
        for (int j = 0; j < 2; ++j) acc[i][j] = (f32x4){0.f,0.f,0.f,0.f};

    gloadB(0); sstoreB(0);
    __syncthreads();
    const int nk = D / 32;
    for (int kt = 0; kt < nk; ++kt){
        const int buf = kt & 1;
        if (kt + 1 < nk) gloadB((kt + 1) * 32);
        short8 af[2], bfr[2];
        af[0]  = *(const short8*)&As[wm + fro][kt * 32 + fk];
        af[1]  = *(const short8*)&As[wm + 16 + fro][kt * 32 + fk];
        bfr[0] = *(const short8*)&Bs[buf][wn + fro][fk];
        bfr[1] = *(const short8*)&Bs[buf][wn + 16 + fro][fk];
        #pragma unroll
        for (int i = 0; i < 2; ++i)
            #pragma unroll
            for (int j = 0; j < 2; ++j)
                acc[i][j] = __builtin_amdgcn_mfma_f32_16x16x32_bf16(af[i], bfr[j], acc[i][j], 0, 0, 0);
        if (kt + 1 < nk){ sstoreB(buf ^ 1); }
        __syncthreads();
    }
    // loop ends with __syncthreads -> Bs region dead, Ctile alias safe

    if (n0 < DIN){
        float* zb = p.zb[dir];
        #pragma unroll
        for (int i = 0; i < 2; ++i){
            #pragma unroll
            for (int j = 0; j < 2; ++j){
                int col = n0 + wn + j * 16 + (lane & 15);
                #pragma unroll
                for (int r = 0; r < 4; ++r){
                    int row = m0 + wm + i * 16 + (lane >> 4) * 4 + r;
                    zb[(size_t)row * DIN + col] = acc[i][j][r];
                }
            }
        }
        return;
    }

    #pragma unroll
    for (int i = 0; i < 2; ++i){
        #pragma unroll
        for (int j = 0; j < 2; ++j){
            int lcol = wn + j * 16 + (lane & 15);
            #pragma unroll
            for (int r = 0; r < 4; ++r){
                int lr = wm + i * 16 + (lane >> 4) * 4 + r;
                Ctile[lr][lcol] = acc[i][j][r];
            }
        }
    }
    __syncthreads();

    if (xi < 18){
        const float* cw = p.cw[dir] + (size_t)layer * CDIM * DCONV;
        const float* cb = p.cb[dir] + (size_t)layer * CDIM;
        float* xy = p.xy[dir];
        float* bc = p.bcb[dir];
        const int c = tid & 63;
        const int cc = n0 - DIN + c;
        const float w0 = cw[cc * DCONV + 0], w1 = cw[cc * DCONV + 1];
        const float w2 = cw[cc * DCONV + 2], w3 = cw[cc * DCONV + 3];
        const float bb = cb[cc];
        #pragma unroll
        for (int rep = 0; rep < 16; ++rep){
            int s = (tid >> 6) + rep * 4;
            float a = bb;
            {
                int sp = s - 3;
                if (sp >= 0) a += w0 * Ctile[dir ? 63 - sp : sp][c];
                sp = s - 2;
                if (sp >= 0) a += w1 * Ctile[dir ? 63 - sp : sp][c];
                sp = s - 1;
                if (sp >= 0) a += w2 * Ctile[dir ? 63 - sp : sp][c];
                a += w3 * Ctile[dir ? 63 - s : s][c];
            }
            float v = silu_f(a);
            if (cc < DIN) xy[(size_t)(b * 64 + s) * DIN + cc] = v;
            else          bc[(size_t)(b * 64 + s) * 128 + (cc - DIN)] = v;
        }
        return;
    }

    {   // dt block
        const float* dtb = p.dtb[dir] + layer * H;
        const float* Al  = p.Alog[dir] + layer * H;
        float* dts  = p.dts[dir];
        float* cums = p.cums[dir];
        int s = tid & 63;
        int l = dir ? (63 - s) : s;
        #pragma unroll
        for (int rep = 0; rep < 2; ++rep){
            int h = (tid >> 6) + rep * 4;
            float raw = Ctile[l][h] + dtb[h];
            float dt = softplus_f(raw);
            float val = -expf(Al[h]) * dt;
            #pragma unroll
            for (int o = 1; o < 64; o <<= 1){
                float u = __shfl_up(val, o);
                if (s >= o) val += u;
            }
            dts[(size_t)(b * 64 + s) * H + h]  = dt;
            cums[(size_t)(b * 64 + s) * H + h] = val;
        }
    }
}

// ---------------- phase: S + mask + PV + gate + ssq (256 tasks, 256 thr)
__device__ void ph_yscan(int task, int tid, unsigned char* SM, const MegaP& p, int layer){
    float (*Bc)[65] = (float(*)[65])SM;                 // 16640
    float (*CX)[65] = (float(*)[65])(SM + 16640);       // 16640
    float (*Am)[65] = (float(*)[65])(SM + 33280);       // 16640
    float* cumS = (float*)(SM + 49920);                 // 256
    float* dtS  = (float*)(SM + 50176);                 // 256
    float (*ssqp)[64] = (float(*)[64])(SM + 50432);     // 1024
    const int h = task & 7, b = (task >> 3) & 15, dir = task >> 7;
    const float* bc   = p.bcb[dir];
    const float* dts  = p.dts[dir];
    const float* cums = p.cums[dir];
    const float* Dp   = p.Dp[dir] + layer * H;
    const float* zb   = p.zb[dir];
    float* xy  = p.xy[dir];
    float* ssq = p.ssq[dir];

    if (tid < 64){
        cumS[tid] = cums[(size_t)(b * L + tid) * H + h];
        dtS[tid]  = dts[(size_t)(b * L + tid) * H + h];
    }
    for (int i = tid; i < 4096; i += 256){
        int s = i >> 6, n = i & 63;
        Bc[s][n] = bc[(size_t)(b * L + s) * 128 + n];
        CX[s][n] = bc[(size_t)(b * L + s) * 128 + 64 + n];
    }
    __syncthreads();
    for (int i = tid; i < 4096; i += 256){
        int s = i >> 6, j = i & 63;
        float v = 0.f;
        if (j <= s){
            float acc = 0.f;
            #pragma unroll
            for (int n = 0; n < 64; ++n) acc += CX[s][n] * Bc[j][n];
            v = acc * expf(cumS[s] - cumS[j]) * dtS[j];
        }
        Am[s][j] = v;
    }
    __syncthreads();
    for (int i = tid; i < 4096; i += 256){
        int j = i >> 6, pp = i & 63;
        CX[j][pp] = xy[(size_t)(b * L + j) * DIN + h * DH + pp];
    }
    __syncthreads();
    {
        const int s = tid & 63, pg = tid >> 6;
        const int l = dir ? (63 - s) : s;
        const size_t row = (size_t)(b * 64 + l);
        const float dp = Dp[h];
        float acc[16];
        #pragma unroll
        for (int pp = 0; pp < 16; ++pp) acc[pp] = dp * CX[s][pg * 16 + pp];
        #pragma unroll
        for (int j = 0; j < 64; ++j){
            float am = Am[s][j];
            #pragma unroll
            for (int pp = 0; pp < 16; ++pp)
                acc[pp] = fmaf(am, CX[j][pg * 16 + pp], acc[pp]);
        }
        const float* zr = zb + row * DIN + h * DH + pg * 16;
        float4 z0 = *(const float4*)(zr);
        float4 z1 = *(const float4*)(zr + 4);
        float4 z2 = *(const float4*)(zr + 8);
        float4 z3 = *(const float4*)(zr + 12);
        float zv[16] = {z0.x,z0.y,z0.z,z0.w, z1.x,z1.y,z1.z,z1.w,
                        z2.x,z2.y,z2.z,z2.w, z3.x,z3.y,z3.z,z3.w};
        float g2 = 0.f;
        float gout[16];
        #pragma unroll
        for (int pp = 0; pp < 16; ++pp){
            float g = acc[pp] * silu_f(zv[pp]);
            gout[pp] = g;
            g2 += g * g;
        }
        ssqp[pg][s] = g2;
        float* dst = xy + row * DIN + h * DH + pg * 16;
        *(float4*)(dst)      = make_float4(gout[0],  gout[1],  gout[2],  gout[3]);
        *(float4*)(dst + 4)  = make_float4(gout[4],  gout[5],  gout[6],  gout[7]);
        *(float4*)(dst + 8)  = make_float4(gout[8],  gout[9],  gout[10], gout[11]);
        *(float4*)(dst + 12) = make_float4(gout[12], gout[13], gout[14], gout[15]);
    }
    __syncthreads();
    if (tid < 64){
        int ll = dir ? (63 - tid) : tid;
        float v = (ssqp[0][tid] + ssqp[1][tid]) + (ssqp[2][tid] + ssqp[3][tid]);
        ssq[(size_t)(b * 64 + ll) * H + h] = v;
    }
}

// ---------------- phase: out-proj GEMM split-K=8 + gate-norm prologue (512 tasks)
__device__ void ph_gemm_out(int task, int tid, unsigned char* SM, const MegaP& p, int layer){
    ushort_t (*As)[64][40] = (ushort_t(*)[64][40])SM;           // 10240
    ushort_t (*Bs)[64][40] = (ushort_t(*)[64][40])(SM + 10240); // 10240
    float* scl = (float*)(SM + 20480);                          // 256
    const int xi = task & 3, mb = (task >> 2) & 15, z = task >> 6;
    const int n0 = xi * 64, m0 = mb * 64;
    const int dir = z >> 2;
    const int kbase = (z & 3) * 128;
    const float* G   = p.xy[dir];
    const float* ssq = p.ssq[dir];
    const float* gnw = p.gn[dir] + (size_t)layer * DIN;
    const ushort_t* B = p.wout_bf + (size_t)(2 * layer + dir) * 131072;
    const int lrow = tid >> 2, lc8 = (tid & 3) * 8;
    const int wave = tid >> 6, lane = tid & 63;
    const int wm = (wave >> 1) * 32, wn = (wave & 1) * 32;
    const int fro = lane & 15, fk = (lane >> 4) * 8;

    if (tid < 64){
        const float* sr = ssq + (size_t)(m0 + tid) * H;
        float v = (sr[0] + sr[1]) + (sr[2] + sr[3]) + (sr[4] + sr[5]) + (sr[6] + sr[7]);
        scl[tid] = rsqrtf(v * (1.f / (float)DIN) + EPS);
    }
    __syncthreads();

    short8 areg; float4 breg;
    auto gload = [&](int kk){
        const float* src = G + (size_t)(m0 + lrow) * DIN + kk + lc8;
        float4 a0 = *(const float4*)(src);
        float4 a1 = *(const float4*)(src + 4);
        const float* gw = gnw + kk + lc8;
        float4 w0 = *(const float4*)(gw);
        float4 w1 = *(const float4*)(gw + 4);
        float sc = scl[lrow];
        ushort_t ta[8] = {f2b(a0.x*sc*w0.x), f2b(a0.y*sc*w0.y), f2b(a0.z*sc*w0.z), f2b(a0.w*sc*w0.w),
                          f2b(a1.x*sc*w1.x), f2b(a1.y*sc*w1.y), f2b(a1.z*sc*w1.z), f2b(a1.w*sc*w1.w)};
        areg = *(short8*)ta;
        breg = *(const float4*)(B + (size_t)(n0 + lrow) * DIN + kk + lc8);
    };
    auto sstore = [&](int buf){
        *(short8*)&As[buf][lrow][lc8] = areg;
        *(float4*)&Bs[buf][lrow][lc8] = breg;
    };

    f32x4 acc[2][2];
    #pragma unroll
    for (int i = 0; i < 2; ++i)
        #pragma unroll
        for (int j = 0; j < 2; ++j) acc[i][j] = (f32x4){0.f,0.f,0.f,0.f};

    const int nk = 4;
    gload(kbase); sstore(0);
    __syncthreads();
    for (int kt = 0; kt < nk; ++kt){
        const int buf = kt & 1;
        if (kt + 1 < nk) gload(kbase + (kt + 1) * 32);
        short8 af[2], bfr[2];
        af[0]  = *(const short8*)&As[buf][wm + fro][fk];
        af[1]  = *(const short8*)&As[buf][wm + 16 + fro][fk];
        bfr[0] = *(const short8*)&Bs[buf][wn + fro][fk];
        bfr[1] = *(const short8*)&Bs[buf][wn + 16 + fro][fk];
        #pragma unroll
        for (int i = 0; i < 2; ++i)
            #pragma unroll
            for (int j = 0; j < 2; ++j)
                acc[i][j] = __builtin_amdgcn_mfma_f32_16x16x32_bf16(af[i], bfr[j], acc[i][j], 0, 0, 0);
        if (kt + 1 < nk){ sstore(buf ^ 1); __syncthreads(); }
    }
    float* Cp = p.partO + (size_t)z * (BATCH * L * D);
    #pragma unroll
    for (int i = 0; i < 2; ++i){
        #pragma unroll
        for (int j = 0; j < 2; ++j){
            int col = n0 + wn + j * 16 + (lane & 15);
            #pragma unroll
            for (int r = 0; r < 4; ++r){
                int row = m0 + wm + i * 16 + (lane >> 4) * 4 + r;
                Cp[(size_t)row * D + col] = acc[i][j][r];
            }
        }
    }
}

// ---------------- phase: out reduce (1024 tasks, layer 0 only)
__device__ void ph_outred(int task, int tid, const MegaP& p){
    int i = task * 256 + tid;
    float v = 0.f;
    #pragma unroll
    for (int r = 0; r < 8; ++r) v += p.partO[i + r * (BATCH * L * D)];
    p.t[i] += 0.5f * v;
}

// ---------------- phase: final rmsnorm + partial mean (128 tasks)
__device__ void ph_finalmean(int task, int tid, unsigned char* SM, const MegaP& p){
    float* sm4 = (float*)SM;
    int b = task & 15, q = task >> 4;
    int d = tid;
    float a = 0.f;
    for (int r = 0; r < 8; ++r){
        int row = b * 64 + q * 8 + r;
        size_t o = (size_t)row * D + d;
        float pv = 0.f;
        #pragma unroll
        for (int u = 0; u < 8; ++u) pv += p.partO[o + (size_t)u * (BATCH * L * D)];
        float v = p.t[o] + 0.5f * pv;
        float ssl = v * v;
        #pragma unroll
        for (int off = 32; off > 0; off >>= 1) ssl += __shfl_down(ssl, off);
        if ((tid & 63) == 0) sm4[tid >> 6] = ssl;
        __syncthreads();
        float ss = sm4[0] + sm4[1] + sm4[2] + sm4[3];
        __syncthreads();
        float sc = rsqrtf(ss / (float)D + EPS);
        a += v * sc;
    }
    p.tm8[(q * BATCH + b) * D + d] = a * (1.f / (float)L) * p.final_w[d];
}

// ---------------- phase: head (63 tasks)
__device__ void ph_head(int task, int tid, unsigned char* SM, const MegaP& p){
    float (*trs)[256] = (float(*)[256])SM;
    int i0 = task * 256;
    int mmin = i0 / NCLS;
    #pragma unroll
    for (int mm = 0; mm < 2; ++mm){
        int m = mmin + mm;
        float v = 0.f;
        if (m < BATCH){
            #pragma unroll
            for (int q = 0; q < 8; ++q)
                v += p.tm8[(q * BATCH + m) * D + tid];
        }
        trs[mm][tid] = v;
    }
    __syncthreads();
    int i = i0 + tid;
    if (i >= BATCH * NCLS) return;
    int m = i / NCLS, n = i - m * NCLS;
    const float* tr = trs[m - mmin];
    const float* hc = p.head_w + n;
    float a0 = 0.f, a1 = 0.f, a2 = 0.f, a3 = 0.f;
    #pragma unroll 4
    for (int k = 0; k < D; k += 4){
        a0 = fmaf(tr[k],     hc[(size_t)k * NCLS],       a0);
        a1 = fmaf(tr[k + 1], hc[(size_t)(k + 1) * NCLS], a1);
        a2 = fmaf(tr[k + 2], hc[(size_t)(k + 2) * NCLS], a2);
        a3 = fmaf(tr[k + 3], hc[(size_t)(k + 3) * NCLS], a3);
    }
    p.out[i] = (a0 + a1) + (a2 + a3) + p.head_b[n];
}

// ---------------- cooperative mega kernel (grid-stride over tasks)
__global__ __launch_bounds__(256) void mega_k(MegaP p){
    __shared__ __align__(16) unsigned char SM[51712];
    cg::grid_group grid = cg::this_grid();
    const int tid = threadIdx.x;
    const int nb = gridDim.x;

    for (int task = blockIdx.x; task < 2208; task += nb){
        if (task < 1696) ph_wconv(task, tid, SM, p);
        else             ph_patch(task - 1696, tid, SM, p);
        __syncthreads();
    }
    grid.sync();
    for (int task = blockIdx.x; task < 1024; task += nb)
        ph_patchred(task, tid, p);
    grid.sync();

    for (int layer = 0; layer < DEPTH; ++layer){
        for (int task = blockIdx.x; task < 608; task += nb){
            ph_gemm_in(task, tid, SM, p, layer);
            __syncthreads();
        }
        grid.sync();
        for (int task = blockIdx.x; task < 256; task += nb){
            ph_yscan(task, tid, SM, p, layer);
            __syncthreads();
        }
        grid.sync();
        for (int task = blockIdx.x; task < 512; task += nb){
            ph_gemm_out(task, tid, SM, p, layer);
            __syncthreads();
        }
        grid.sync();
        if (layer == 0){
            for (int task = blockIdx.x; task < 1024; task += nb)
                ph_outred(task, tid, p);
            grid.sync();
        }
    }

    for (int task = blockIdx.x; task < 128; task += nb){
        ph_finalmean(task, tid, SM, p);
        __syncthreads();
    }
    grid.sync();
    for (int task = blockIdx.x; task < 63; task += nb){
        ph_head(task, tid, SM, p);
        __syncthreads();
    }
}

// ---------------- fallback wrappers (same device code, one task per block)
__global__ __launch_bounds__(256) void w_phase0(MegaP p){
    __shared__ __align__(16) unsigned char SM[20480];
    int task = blockIdx.x;
    if (task < 1696) ph_wconv(task, threadIdx.x, SM, p);
    else             ph_patch(task - 1696, threadIdx.x, SM, p);
}
__global__ __launch_bounds__(256) void w_patchred(MegaP p){
    ph_patchred(blockIdx.x, threadIdx.x, p);
}
__global__ __launch_bounds__(256) void w_gemm_in(MegaP p, int layer){
    __shared__ __align__(16) unsigned char SM[51200];
    ph_gemm_in(blockIdx.x, threadIdx.x, SM, p, layer);
}
__global__ __launch_bounds__(256) void w_yscan(MegaP p, int layer){
    __shared__ __align__(16) unsigned char SM[51712];
    ph_yscan(blockIdx.x, threadIdx.x, SM, p, layer);
}
__global__ __launch_bounds__(256) void w_gemm_out(MegaP p, int layer){
    __shared__ __align__(16) unsigned char SM[20736];
    ph_gemm_out(blockIdx.x, threadIdx.x, SM, p, layer);
}
__global__ __launch_bounds__(256) void w_outred(MegaP p){
    ph_outred(blockIdx.x, threadIdx.x, p);
}
__global__ __launch_bounds__(256) void w_finalmean(MegaP p){
    __shared__ __align__(16) unsigned char SM[16];
    ph_finalmean(blockIdx.x, threadIdx.x, SM, p);
}
__global__ __launch_bounds__(256) void w_head(MegaP p){
    __shared__ __align__(16) unsigned char SM[2048];
    ph_head(blockIdx.x, threadIdx.x, SM, p);
}

extern "C" void kernel_launch(void* const* d_in, const int* in_sizes, int n_in,
                              void* d_out, int out_size, void* d_ws, size_t ws_size,
                              hipStream_t stream){
    (void)in_sizes; (void)n_in; (void)out_size; (void)ws_size;
    MegaP p;
    p.x       = (const float*)d_in[0];
    p.patch_w = (const float*)d_in[1];
    p.patch_b = (const float*)d_in[2];
    p.pos     = (const float*)d_in[3];
    p.norms_w = (const float*)d_in[4];
    p.final_w = (const float*)d_in[5];
    p.head_w  = (const float*)d_in[6];
    p.head_b  = (const float*)d_in[7];
    p.Win[0]  = (const float*)d_in[8];   p.Win[1]  = (const float*)d_in[16];
    p.cw[0]   = (const float*)d_in[9];   p.cw[1]   = (const float*)d_in[17];
    p.cb[0]   = (const float*)d_in[10];  p.cb[1]   = (const float*)d_in[18];
    p.dtb[0]  = (const float*)d_in[11];  p.dtb[1]  = (const float*)d_in[19];
    p.Alog[0] = (const float*)d_in[12];  p.Alog[1] = (const float*)d_in[20];
    p.Dp[0]   = (const float*)d_in[13];  p.Dp[1]   = (const float*)d_in[21];
    p.gn[0]   = (const float*)d_in[14];  p.gn[1]   = (const float*)d_in[22];
    p.Wout[0] = (const float*)d_in[15];  p.Wout[1] = (const float*)d_in[23];

    float* ws = (float*)d_ws;
    p.t      = ws;                    // 262144
    p.tm8    = p.t      + 262144;     // 32768
    p.zb[0]  = p.tm8    + 32768;      // 524288
    p.zb[1]  = p.zb[0]  + 524288;
    p.xy[0]  = p.zb[1]  + 524288;     // 524288
    p.xy[1]  = p.xy[0]  + 524288;
    p.bcb[0] = p.xy[1]  + 524288;     // 131072
    p.bcb[1] = p.bcb[0] + 131072;
    p.dts[0] = p.bcb[1] + 131072;     // 8192 x6
    p.dts[1] = p.dts[0] + 8192;
    p.cums[0]= p.dts[1] + 8192;
    p.cums[1]= p.cums[0]+ 8192;
    p.ssq[0] = p.cums[1]+ 8192;
    p.ssq[1] = p.ssq[0] + 8192;
    p.partP  = p.ssq[1] + 8192;       // 2097152
    p.partO  = p.partP  + 2097152;    // 2097152
    float* f32end = p.partO + 2097152;
    p.win_bf  = (ushort_t*)f32end;    // 4 x 296960
    p.wout_bf = p.win_bf + 1187840;   // 4 x 131072
    p.out = (float*)d_out;

    // --- deterministic launch-path selection ---
    int dev = 0;
    hipGetDevice(&dev);
    int coop = 0, ncu = 0, maxb = 0;
    hipDeviceGetAttribute(&coop, hipDeviceAttributeCooperativeLaunch, dev);
    hipDeviceGetAttribute(&ncu, hipDeviceAttributeMultiprocessorCount, dev);
    hipOccupancyMaxActiveBlocksPerMultiprocessor(&maxb, (const void*)mega_k, 256, 0);

    hipError_t st = hipErrorUnknown;
    if (coop && maxb > 0 && ncu > 0){
        int nblk = maxb * ncu;
        if (nblk > 2208) nblk = 2208;
        void* args[] = { &p };
        st = hipLaunchCooperativeKernel((void*)mega_k, dim3(nblk), dim3(256), args, 0, stream);
    }
    if (st != hipSuccess){
        // fallback: identical math via per-phase launches
        w_phase0<<<2208, 256, 0, stream>>>(p);
        w_patchred<<<1024, 256, 0, stream>>>(p);
        for (int layer = 0; layer < DEPTH; ++layer){
            w_gemm_in<<<608, 256, 0, stream>>>(p, layer);
            w_yscan<<<256, 256, 0, stream>>>(p, layer);
            w_gemm_out<<<512, 256, 0, stream>>>(p, layer);
            if (layer == 0)
                w_outred<<<1024, 256, 0, stream>>>(p);
        }
        w_finalmean<<<128, 256, 0, stream>>>(p);
        w_head<<<63, 256, 0, stream>>>(p);
    }
}

// Round 13
// 140.581 us; speedup vs baseline: 3.5016x; 3.5016x over previous
//
#include <hip/hip_runtime.h>
#include <hip/hip_bf16.h>
#include <math.h>

#define IMG 128
#define PATCH 16
#define L 64
#define D 256
#define DIN 512
#define DH 64
#define H 8
#define NSTATE 64
#define DCONV 4
#define DEPTH 2
#define NCLS 1000
#define BATCH 16
#define DINPROJ 1160   // 2*DIN + 2*N + H
#define CDIM 640       // DIN + 2*N
#define EPS 1e-6f
#define SLAB (BATCH * L * D)   // 262144

typedef __attribute__((ext_vector_type(8))) short short8;
typedef __attribute__((ext_vector_type(4))) float f32x4;
typedef __attribute__((ext_vector_type(4))) unsigned short us4;
typedef unsigned short ushort_t;

__device__ __forceinline__ int snake_tok(int s){
    int r = s >> 3, c = s & 7;
    return (r & 1) ? (r * 8 + (7 - c)) : (r * 8 + c);
}
__device__ __forceinline__ float silu_f(float x){ return x / (1.f + expf(-x)); }
__device__ __forceinline__ float softplus_f(float x){ return x > 20.f ? x : log1pf(expf(x)); }
__device__ __forceinline__ ushort_t f2b(float f){
    __hip_bfloat16 h = __float2bfloat16(f);
    return *(ushort_t*)&h;
}

// ---------------- phase 0: weight convert (1696 tasks) + patch GEMM split-K=2 (128 tasks)
__global__ __launch_bounds__(256) void wconv_patch_k(
    const float* __restrict__ Win0, const float* __restrict__ Win1,
    const float* __restrict__ Wout0, const float* __restrict__ Wout1,
    ushort_t* __restrict__ wbuf,
    const float* __restrict__ x, const float* __restrict__ PW,
    float* __restrict__ partP)
{
    __shared__ __align__(16) unsigned char SM[20480];
    const int task = blockIdx.x;
    const int tid = threadIdx.x;
    if (task < 1696){
        float (*sm)[33] = (float(*)[33])SM;
        const float* src; ushort_t* dst; int R, C, ctiles, tile;
        if (task < 1184){
            int z = task / 296; tile = task - z * 296;
            src = (z & 1 ? Win1 : Win0) + (size_t)(z >> 1) * D * DINPROJ;
            dst = wbuf + (size_t)z * 296960;
            R = D; C = DINPROJ; ctiles = 37;
        } else {
            int k = task - 1184;
            int z = k >> 7; tile = k & 127;
            src = (z & 1 ? Wout1 : Wout0) + (size_t)(z >> 1) * DIN * D;
            dst = wbuf + 1187840 + (size_t)z * 131072;
            R = DIN; C = D; ctiles = 8;
        }
        int cx = tile % ctiles, ry = tile / ctiles;
        int c0 = cx * 32, r0 = ry * 32;
        int tx = tid & 31, ty = tid >> 5;
        #pragma unroll
        for (int k = 0; k < 4; ++k){
            int r = r0 + ty + 8 * k, c = c0 + tx;
            sm[ty + 8 * k][tx] = (c < C) ? src[(size_t)r * C + c] : 0.f;
        }
        __syncthreads();
        #pragma unroll
        for (int k = 0; k < 4; ++k){
            int dr = c0 + ty + 8 * k, dc = r0 + tx;
            if (dr < C) dst[(size_t)dr * R + dc] = f2b(sm[tx][ty + 8 * k]);
        }
        return;
    }
    // ---- patch GEMM: 128 tasks = xi(4) x b(16) x split(2), K=384 each ----
    ushort_t (*As)[64][40] = (ushort_t(*)[64][40])SM;
    ushort_t (*Bs)[64][40] = (ushort_t(*)[64][40])(SM + 10240);
    const int pt = task - 1696;
    const int xi = pt & 3, b = (pt >> 2) & 15, split = pt >> 6;
    const int n0 = xi * 64;
    const int kbase = split * 384;
    const int lrow = tid >> 2, lc8 = (tid & 3) * 8;
    const int tok = snake_tok(lrow), gy = tok >> 3, gx = tok & 7;
    const float* xb = x + (size_t)b * 3 * IMG * IMG;
    const int wave = tid >> 6, lane = tid & 63;
    const int wm = (wave >> 1) * 32, wn = (wave & 1) * 32;
    const int fro = lane & 15, fk = (lane >> 4) * 8;

    f32x4 acc[2][2];
    #pragma unroll
    for (int i = 0; i < 2; ++i)
        #pragma unroll
        for (int j = 0; j < 2; ++j) acc[i][j] = (f32x4){0.f,0.f,0.f,0.f};

    short8 areg, breg;
    auto gload = [&](int kk){
        int k = kk + lc8;
        int c = k >> 8, rem = k & 255, py = rem >> 4, px = rem & 15;
        const float* srcA = xb + ((size_t)c * IMG + gy * PATCH + py) * IMG + gx * PATCH + px;
        float4 a0 = *(const float4*)(srcA);
        float4 a1 = *(const float4*)(srcA + 4);
        ushort_t ta[8] = {f2b(a0.x),f2b(a0.y),f2b(a0.z),f2b(a0.w),
                          f2b(a1.x),f2b(a1.y),f2b(a1.z),f2b(a1.w)};
        areg = *(short8*)ta;
        const float* srcB = PW + (size_t)(n0 + lrow) * 768 + kk + lc8;
        float4 b0 = *(const float4*)(srcB);
        float4 b1 = *(const float4*)(srcB + 4);
        ushort_t tb[8] = {f2b(b0.x),f2b(b0.y),f2b(b0.z),f2b(b0.w),
                          f2b(b1.x),f2b(b1.y),f2b(b1.z),f2b(b1.w)};
        breg = *(short8*)tb;
    };
    auto sstore = [&](int buf){
        *(short8*)&As[buf][lrow][lc8] = areg;
        *(short8*)&Bs[buf][lrow][lc8] = breg;
    };

    const int nk = 12;
    gload(kbase); sstore(0);
    __syncthreads();
    for (int kt = 0; kt < nk; ++kt){
        const int buf = kt & 1;
        if (kt + 1 < nk) gload(kbase + (kt + 1) * 32);
        short8 af[2], bfr[2];
        af[0]  = *(const short8*)&As[buf][wm + fro][fk];
        af[1]  = *(const short8*)&As[buf][wm + 16 + fro][fk];
        bfr[0] = *(const short8*)&Bs[buf][wn + fro][fk];
        bfr[1] = *(const short8*)&Bs[buf][wn + 16 + fro][fk];
        #pragma unroll
        for (int i = 0; i < 2; ++i)
            #pragma unroll
            for (int j = 0; j < 2; ++j)
                acc[i][j] = __builtin_amdgcn_mfma_f32_16x16x32_bf16(af[i], bfr[j], acc[i][j], 0, 0, 0);
        if (kt + 1 < nk) sstore(buf ^ 1);
        __syncthreads();
    }
    float* Cp = partP + (size_t)split * SLAB;
    #pragma unroll
    for (int i = 0; i < 2; ++i){
        #pragma unroll
        for (int j = 0; j < 2; ++j){
            int col = n0 + wn + j * 16 + (lane & 15);
            #pragma unroll
            for (int r = 0; r < 4; ++r){
                int srow = wm + i * 16 + (lane >> 4) * 4 + r;
                Cp[(size_t)(b * 64 + srow) * D + col] = acc[i][j][r];
            }
        }
    }
}

// ---------------- in-proj GEMM: prologue recomputes t inline (patch sums [+0.5*outL0]),
// rmsnorm -> bf16 A; conv/dt epilogue as before. grid (19,16,2).
__global__ __launch_bounds__(256) void gemm_in_k(
    const float* __restrict__ partP, const float* __restrict__ pb,
    const float* __restrict__ pos, const float* __restrict__ pO,   // null for layer 0
    const float* __restrict__ nw,
    const ushort_t* __restrict__ B0, const ushort_t* __restrict__ B1,
    const float* __restrict__ cw0, const float* __restrict__ cw1,
    const float* __restrict__ cb0, const float* __restrict__ cb1,
    const float* __restrict__ dtb0, const float* __restrict__ dtb1,
    const float* __restrict__ Al0, const float* __restrict__ Al1,
    float* __restrict__ zb0, float* __restrict__ zb1,
    float* __restrict__ xy0, float* __restrict__ xy1,
    float* __restrict__ bc0, float* __restrict__ bc1,
    float* __restrict__ dts0, float* __restrict__ dts1,
    float* __restrict__ cums0, float* __restrict__ cums1)
{
    __shared__ __align__(16) ushort_t As[64][264];
    __shared__ __align__(16) ushort_t Bs[2][64][40];
    __shared__ float Ctile[64][68];        // aliases Bs region? no: separate (fits 51200+17408? keep separate)
    const int dir = blockIdx.z;
    const ushort_t* __restrict__ Bw = dir ? B1 : B0;
    const int tid = threadIdx.x;
    const int m0 = blockIdx.y * 64, n0 = blockIdx.x * 64;
    const int b = blockIdx.y;
    const int arow = tid >> 2;
    const int wave = tid >> 6, lane = tid & 63;
    const int wm = (wave >> 1) * 32, wn = (wave & 1) * 32;
    const int fro = lane & 15, fk = (lane >> 4) * 8;

    {   // prologue: recompute t row, rmsnorm -> As bf16 (single pass, register stash)
        const int row = m0 + arow;
        const int tokr = snake_tok(row & 63);
        float4 vr[16];
        float ss = 0.f;
        #pragma unroll
        for (int i = 0; i < 16; ++i){
            int c = (tid & 3) * 4 + i * 16;
            size_t o = (size_t)row * D + c;
            float4 p0 = *(const float4*)(partP + o);
            float4 p1 = *(const float4*)(partP + SLAB + o);
            float4 bb = *(const float4*)(pb + c);
            float4 ps = *(const float4*)(pos + (size_t)tokr * D + c);
            float4 v;
            v.x = p0.x + p1.x + bb.x + ps.x;
            v.y = p0.y + p1.y + bb.y + ps.y;
            v.z = p0.z + p1.z + bb.z + ps.z;
            v.w = p0.w + p1.w + bb.w + ps.w;
            if (pO){
                float4 o0 = *(const float4*)(pO + o);
                float4 o1 = *(const float4*)(pO + SLAB + o);
                float4 o2 = *(const float4*)(pO + 2 * SLAB + o);
                float4 o3 = *(const float4*)(pO + 3 * SLAB + o);
                v.x += 0.5f * ((o0.x + o1.x) + (o2.x + o3.x));
                v.y += 0.5f * ((o0.y + o1.y) + (o2.y + o3.y));
                v.z += 0.5f * ((o0.z + o1.z) + (o2.z + o3.z));
                v.w += 0.5f * ((o0.w + o1.w) + (o2.w + o3.w));
            }
            vr[i] = v;
            ss += v.x*v.x + v.y*v.y + v.z*v.z + v.w*v.w;
        }
        ss += __shfl_xor(ss, 1);
        ss += __shfl_xor(ss, 2);
        float sc = rsqrtf(ss * (1.f / (float)D) + EPS);
        #pragma unroll
        for (int i = 0; i < 16; ++i){
            int c = (tid & 3) * 4 + i * 16;
            float4 w = *(const float4*)(nw + c);
            float4 v = vr[i];
            us4 ov = {f2b(v.x*sc*w.x), f2b(v.y*sc*w.y), f2b(v.z*sc*w.z), f2b(v.w*sc*w.w)};
            *(us4*)&As[arow][c] = ov;
        }
    }
    const int lrow = tid >> 2, lc8 = (tid & 3) * 8;
    float4 breg;
    auto gloadB = [&](int kk){
        int gn = n0 + lrow;
        if (gn < DINPROJ) breg = *(const float4*)(Bw + (size_t)gn * D + kk + lc8);
        else breg = make_float4(0.f,0.f,0.f,0.f);
    };
    auto sstoreB = [&](int buf){ *(float4*)&Bs[buf][lrow][lc8] = breg; };

    f32x4 acc[2][2];
    #pragma unroll
    for (int i = 0; i < 2; ++i)
        #pragma unroll
        for (int j = 0; j < 2; ++j) acc[i][j] = (f32x4){0.f,0.f,0.f,0.f};

    gloadB(0); sstoreB(0);
    __syncthreads();
    const int nk = D / 32;
    for (int kt = 0; kt < nk; ++kt){
        const int buf = kt & 1;
        if (kt + 1 < nk) gloadB((kt + 1) * 32);
        short8 af[2], bfr[2];
        af[0]  = *(const short8*)&As[wm + fro][kt * 32 + fk];
        af[1]  = *(const short8*)&As[wm + 16 + fro][kt * 32 + fk];
        bfr[0] = *(const short8*)&Bs[buf][wn + fro][fk];
        bfr[1] = *(const short8*)&Bs[buf][wn + 16 + fro][fk];
        #pragma unroll
        for (int i = 0; i < 2; ++i)
            #pragma unroll
            for (int j = 0; j < 2; ++j)
                acc[i][j] = __builtin_amdgcn_mfma_f32_16x16x32_bf16(af[i], bfr[j], acc[i][j], 0, 0, 0);
        if (kt + 1 < nk) sstoreB(buf ^ 1);
        __syncthreads();
    }

    if (n0 < DIN){
        float* zb = dir ? zb1 : zb0;
        #pragma unroll
        for (int i = 0; i < 2; ++i){
            #pragma unroll
            for (int j = 0; j < 2; ++j){
                int col = n0 + wn + j * 16 + (lane & 15);
                #pragma unroll
                for (int r = 0; r < 4; ++r){
                    int row = m0 + wm + i * 16 + (lane >> 4) * 4 + r;
                    zb[(size_t)row * DIN + col] = acc[i][j][r];
                }
            }
        }
        return;
    }

    #pragma unroll
    for (int i = 0; i < 2; ++i){
        #pragma unroll
        for (int j = 0; j < 2; ++j){
            int lcol = wn + j * 16 + (lane & 15);
            #pragma unroll
            for (int r = 0; r < 4; ++r){
                int lr = wm + i * 16 + (lane >> 4) * 4 + r;
                Ctile[lr][lcol] = acc[i][j][r];
            }
        }
    }
    __syncthreads();

    if (blockIdx.x < 18){
        const float* cw = dir ? cw1 : cw0;
        const float* cb = dir ? cb1 : cb0;
        float* xy = dir ? xy1 : xy0;
        float* bc = dir ? bc1 : bc0;
        const int c = tid & 63;
        const int cc = n0 - DIN + c;
        const float w0 = cw[cc * DCONV + 0], w1 = cw[cc * DCONV + 1];
        const float w2 = cw[cc * DCONV + 2], w3 = cw[cc * DCONV + 3];
        const float bb = cb[cc];
        #pragma unroll
        for (int rep = 0; rep < 16; ++rep){
            int s = (tid >> 6) + rep * 4;
            float a = bb;
            {
                int sp = s - 3;
                if (sp >= 0) a += w0 * Ctile[dir ? 63 - sp : sp][c];
                sp = s - 2;
                if (sp >= 0) a += w1 * Ctile[dir ? 63 - sp : sp][c];
                sp = s - 1;
                if (sp >= 0) a += w2 * Ctile[dir ? 63 - sp : sp][c];
                a += w3 * Ctile[dir ? 63 - s : s][c];
            }
            float v = silu_f(a);
            if (cc < DIN) xy[(size_t)(b * 64 + s) * DIN + cc] = v;
            else          bc[(size_t)(b * 64 + s) * 128 + (cc - DIN)] = v;
        }
        return;
    }

    {   // dt block
        const float* dtb = dir ? dtb1 : dtb0;
        const float* Al  = dir ? Al1  : Al0;
        float* dts  = dir ? dts1  : dts0;
        float* cums = dir ? cums1 : cums0;
        int s = tid & 63;
        int l = dir ? (63 - s) : s;
        #pragma unroll
        for (int rep = 0; rep < 2; ++rep){
            int h = (tid >> 6) + rep * 4;
            float raw = Ctile[l][h] + dtb[h];
            float dt = softplus_f(raw);
            float val = -expf(Al[h]) * dt;
            #pragma unroll
            for (int o = 1; o < 64; o <<= 1){
                float u = __shfl_up(val, o);
                if (s >= o) val += u;
            }
            dts[(size_t)(b * 64 + s) * H + h]  = dt;
            cums[(size_t)(b * 64 + s) * H + h] = val;
        }
    }
}

// ---------------- fused S + mask + PV + gate + ssq; grid (H, B, 2), 512 thr
__global__ __launch_bounds__(512) void yscan2_k(
    const float* __restrict__ bc0, const float* __restrict__ bc1,
    const float* __restrict__ dts0, const float* __restrict__ dts1,
    const float* __restrict__ cums0, const float* __restrict__ cums1,
    const float* __restrict__ Dp0, const float* __restrict__ Dp1,
    const float* __restrict__ zb0, const float* __restrict__ zb1,
    float* __restrict__ xy0, float* __restrict__ xy1,
    float* __restrict__ ssq0, float* __restrict__ ssq1)
{
    __shared__ float Bc[64][65];
    __shared__ float CX[64][65];
    __shared__ float Am[64][65];
    __shared__ float cumS[64], dtS[64];
    __shared__ float ssqp[8][64];
    const int h = blockIdx.x, b = blockIdx.y, dir = blockIdx.z;
    const float* bc   = dir ? bc1   : bc0;
    const float* dts  = dir ? dts1  : dts0;
    const float* cums = dir ? cums1 : cums0;
    const float* Dp   = dir ? Dp1   : Dp0;
    const float* zb   = dir ? zb1   : zb0;
    float* xy  = dir ? xy1  : xy0;
    float* ssq = dir ? ssq1 : ssq0;
    const int t = threadIdx.x;

    if (t < 64){
        cumS[t] = cums[(size_t)(b * L + t) * H + h];
        dtS[t]  = dts[(size_t)(b * L + t) * H + h];
    }
    for (int i = t; i < 4096; i += 512){
        int s = i >> 6, n = i & 63;
        Bc[s][n] = bc[(size_t)(b * L + s) * 128 + n];
        CX[s][n] = bc[(size_t)(b * L + s) * 128 + 64 + n];
    }
    __syncthreads();
    for (int i = t; i < 4096; i += 512){
        int s = i >> 6, j = i & 63;
        float v = 0.f;
        if (j <= s){
            float acc = 0.f;
            #pragma unroll
            for (int n = 0; n < 64; ++n) acc += CX[s][n] * Bc[j][n];
            v = acc * expf(cumS[s] - cumS[j]) * dtS[j];
        }
        Am[s][j] = v;
    }
    __syncthreads();
    for (int i = t; i < 4096; i += 512){
        int j = i >> 6, pp = i & 63;
        CX[j][pp] = xy[(size_t)(b * L + j) * DIN + h * DH + pp];
    }
    __syncthreads();
    {
        const int s = t & 63, pg = t >> 6;
        const int l = dir ? (63 - s) : s;
        const size_t row = (size_t)(b * 64 + l);
        const float dp = Dp[h];
        float acc[8];
        #pragma unroll
        for (int pp = 0; pp < 8; ++pp) acc[pp] = dp * CX[s][pg * 8 + pp];
        #pragma unroll
        for (int j = 0; j < 64; ++j){
            float am = Am[s][j];
            #pragma unroll
            for (int pp = 0; pp < 8; ++pp)
                acc[pp] = fmaf(am, CX[j][pg * 8 + pp], acc[pp]);
        }
        const float* zr = zb + row * DIN + h * DH + pg * 8;
        float4 z0 = *(const float4*)(zr);
        float4 z1 = *(const float4*)(zr + 4);
        float zv[8] = {z0.x, z0.y, z0.z, z0.w, z1.x, z1.y, z1.z, z1.w};
        float g2 = 0.f;
        float gout[8];
        #pragma unroll
        for (int pp = 0; pp < 8; ++pp){
            float g = acc[pp] * silu_f(zv[pp]);
            gout[pp] = g;
            g2 += g * g;
        }
        ssqp[pg][s] = g2;
        float* dst = xy + row * DIN + h * DH + pg * 8;
        *(float4*)(dst)     = make_float4(gout[0], gout[1], gout[2], gout[3]);
        *(float4*)(dst + 4) = make_float4(gout[4], gout[5], gout[6], gout[7]);
    }
    __syncthreads();
    if (t < 64){
        int ll = dir ? (63 - t) : t;
        float v = 0.f;
        #pragma unroll
        for (int q = 0; q < 8; ++q) v += ssqp[q][t];
        ssq[(size_t)(b * 64 + ll) * H + h] = v;
    }
}

// ---------------- out-proj GEMM split-K=4 (dir x 2 halves) + gate-norm prologue; grid (4,16,4)
__global__ __launch_bounds__(256) void gemm_out_k(
    const float* __restrict__ G0, const float* __restrict__ G1,
    const float* __restrict__ ssq0, const float* __restrict__ ssq1,
    const float* __restrict__ gn0, const float* __restrict__ gn1,
    const ushort_t* __restrict__ B0, const ushort_t* __restrict__ B1,
    float* __restrict__ part)
{
    __shared__ __align__(16) ushort_t As[2][64][40];
    __shared__ __align__(16) ushort_t Bs[2][64][40];
    __shared__ float scl[64];
    const int tid = threadIdx.x;
    const int n0 = blockIdx.x * 64, m0 = blockIdx.y * 64;
    const int z = blockIdx.z;
    const int dir = z >> 1;
    const int kbase = (z & 1) * 256;
    const float* __restrict__ G   = dir ? G1   : G0;
    const float* __restrict__ ssq = dir ? ssq1 : ssq0;
    const float* __restrict__ gnw = dir ? gn1  : gn0;
    const ushort_t* __restrict__ B = dir ? B1 : B0;
    const int lrow = tid >> 2, lc8 = (tid & 3) * 8;
    const int wave = tid >> 6, lane = tid & 63;
    const int wm = (wave >> 1) * 32, wn = (wave & 1) * 32;
    const int fro = lane & 15, fk = (lane >> 4) * 8;

    if (tid < 64){
        const float* sr = ssq + (size_t)(m0 + tid) * H;
        float v = (sr[0] + sr[1]) + (sr[2] + sr[3]) + (sr[4] + sr[5]) + (sr[6] + sr[7]);
        scl[tid] = rsqrtf(v * (1.f / (float)DIN) + EPS);
    }
    __syncthreads();

    short8 areg; float4 breg;
    auto gload = [&](int kk){
        const float* src = G + (size_t)(m0 + lrow) * DIN + kk + lc8;
        float4 a0 = *(const float4*)(src);
        float4 a1 = *(const float4*)(src + 4);
        const float* gw = gnw + kk + lc8;
        float4 w0 = *(const float4*)(gw);
        float4 w1 = *(const float4*)(gw + 4);
        float sc = scl[lrow];
        ushort_t ta[8] = {f2b(a0.x*sc*w0.x), f2b(a0.y*sc*w0.y), f2b(a0.z*sc*w0.z), f2b(a0.w*sc*w0.w),
                          f2b(a1.x*sc*w1.x), f2b(a1.y*sc*w1.y), f2b(a1.z*sc*w1.z), f2b(a1.w*sc*w1.w)};
        areg = *(short8*)ta;
        breg = *(const float4*)(B + (size_t)(n0 + lrow) * DIN + kk + lc8);
    };
    auto sstore = [&](int buf){
        *(short8*)&As[buf][lrow][lc8] = areg;
        *(float4*)&Bs[buf][lrow][lc8] = breg;
    };

    f32x4 acc[2][2];
    #pragma unroll
    for (int i = 0; i < 2; ++i)
        #pragma unroll
        for (int j = 0; j < 2; ++j) acc[i][j] = (f32x4){0.f,0.f,0.f,0.f};

    const int nk = 8;
    gload(kbase); sstore(0);
    __syncthreads();
    for (int kt = 0; kt < nk; ++kt){
        const int buf = kt & 1;
        if (kt + 1 < nk) gload(kbase + (kt + 1) * 32);
        short8 af[2], bfr[2];
        af[0]  = *(const short8*)&As[buf][wm + fro][fk];
        af[1]  = *(const short8*)&As[buf][wm + 16 + fro][fk];
        bfr[0] = *(const short8*)&Bs[buf][wn + fro][fk];
        bfr[1] = *(const short8*)&Bs[buf][wn + 16 + fro][fk];
        #pragma unroll
        for (int i = 0; i < 2; ++i)
            #pragma unroll
            for (int j = 0; j < 2; ++j)
                acc[i][j] = __builtin_amdgcn_mfma_f32_16x16x32_bf16(af[i], bfr[j], acc[i][j], 0, 0, 0);
        if (kt + 1 < nk) sstore(buf ^ 1);
        __syncthreads();
    }
    float* Cp = part + (size_t)z * SLAB;
    #pragma unroll
    for (int i = 0; i < 2; ++i){
        #pragma unroll
        for (int j = 0; j < 2; ++j){
            int col = n0 + wn + j * 16 + (lane & 15);
            #pragma unroll
            for (int r = 0; r < 4; ++r){
                int row = m0 + wm + i * 16 + (lane >> 4) * 4 + r;
                Cp[(size_t)row * D + col] = acc[i][j][r];
            }
        }
    }
}

// ---------------- final: t recomputed from partP + 0.5*(partO_L0 + partO_L1),
// rmsnorm rows, partial mean; grid (B, 8)
__global__ void finalmean_k(const float* __restrict__ partP, const float* __restrict__ pb,
                            const float* __restrict__ pos,
                            const float* __restrict__ pO0, const float* __restrict__ pO1,
                            const float* __restrict__ fw, float* __restrict__ tm8){
    __shared__ float sm4[4];
    int b = blockIdx.x, q = blockIdx.y;
    int d = threadIdx.x;
    float a = 0.f;
    for (int r = 0; r < 8; ++r){
        int row = b * 64 + q * 8 + r;
        int tokr = snake_tok(row & 63);
        size_t o = (size_t)row * D + d;
        float v = (partP[o] + partP[SLAB + o]) + pb[d] + pos[(size_t)tokr * D + d];
        v += 0.5f * ((pO0[o] + pO0[SLAB + o]) + (pO0[2 * SLAB + o] + pO0[3 * SLAB + o]));
        v += 0.5f * ((pO1[o] + pO1[SLAB + o]) + (pO1[2 * SLAB + o] + pO1[3 * SLAB + o]));
        float ssl = v * v;
        #pragma unroll
        for (int off = 32; off > 0; off >>= 1) ssl += __shfl_down(ssl, off);
        if ((threadIdx.x & 63) == 0) sm4[threadIdx.x >> 6] = ssl;
        __syncthreads();
        float ss = sm4[0] + sm4[1] + sm4[2] + sm4[3];
        __syncthreads();
        float sc = rsqrtf(ss / (float)D + EPS);
        a += v * sc;
    }
    tm8[(q * BATCH + b) * D + d] = a * (1.f / (float)L) * fw[d];
}

// ---------------- head: single kernel, K=256, tm8 slabs summed in LDS, +bias
__global__ void head_k(const float* __restrict__ tm8, const float* __restrict__ hw,
                       const float* __restrict__ hb, float* __restrict__ out){
    __shared__ float trs[2][256];
    int i0 = blockIdx.x * 256;
    int mmin = i0 / NCLS;
    int t = threadIdx.x;
    #pragma unroll
    for (int mm = 0; mm < 2; ++mm){
        int m = mmin + mm;
        float v = 0.f;
        if (m < BATCH){
            #pragma unroll
            for (int q = 0; q < 8; ++q)
                v += tm8[(q * BATCH + m) * D + t];
        }
        trs[mm][t] = v;
    }
    __syncthreads();
    int i = i0 + t;
    if (i >= BATCH * NCLS) return;
    int m = i / NCLS, n = i - m * NCLS;
    const float* tr = trs[m - mmin];
    const float* hc = hw + n;
    float a0 = 0.f, a1 = 0.f, a2 = 0.f, a3 = 0.f;
    #pragma unroll 4
    for (int k = 0; k < D; k += 4){
        a0 = fmaf(tr[k],     hc[(size_t)k * NCLS],       a0);
        a1 = fmaf(tr[k + 1], hc[(size_t)(k + 1) * NCLS], a1);
        a2 = fmaf(tr[k + 2], hc[(size_t)(k + 2) * NCLS], a2);
        a3 = fmaf(tr[k + 3], hc[(size_t)(k + 3) * NCLS], a3);
    }
    out[i] = (a0 + a1) + (a2 + a3) + hb[n];
}

extern "C" void kernel_launch(void* const* d_in, const int* in_sizes, int n_in,
                              void* d_out, int out_size, void* d_ws, size_t ws_size,
                              hipStream_t stream){
    (void)in_sizes; (void)n_in; (void)out_size; (void)ws_size;
    const float* x       = (const float*)d_in[0];
    const float* patch_w = (const float*)d_in[1];
    const float* patch_b = (const float*)d_in[2];
    const float* pos     = (const float*)d_in[3];
    const float* norms_w = (const float*)d_in[4];
    const float* final_w = (const float*)d_in[5];
    const float* head_w  = (const float*)d_in[6];
    const float* head_b  = (const float*)d_in[7];
    const float* Win[2]  = {(const float*)d_in[8],  (const float*)d_in[16]};
    const float* cw[2]   = {(const float*)d_in[9],  (const float*)d_in[17]};
    const float* cb[2]   = {(const float*)d_in[10], (const float*)d_in[18]};
    const float* dtb[2]  = {(const float*)d_in[11], (const float*)d_in[19]};
    const float* Alog[2] = {(const float*)d_in[12], (const float*)d_in[20]};
    const float* Dp[2]   = {(const float*)d_in[13], (const float*)d_in[21]};
    const float* gn[2]   = {(const float*)d_in[14], (const float*)d_in[22]};
    const float* Wout[2] = {(const float*)d_in[15], (const float*)d_in[23]};

    float* ws = (float*)d_ws;
    float* tm8   = ws;                   // 32768
    float* zb0   = tm8   + 32768;        // 524288
    float* zb1   = zb0   + 524288;
    float* xy0   = zb1   + 524288;       // 524288
    float* xy1   = xy0   + 524288;
    float* bc0   = xy1   + 524288;       // 131072
    float* bc1   = bc0   + 131072;
    float* dts0  = bc1   + 131072;       // 8192 x6
    float* dts1  = dts0  + 8192;
    float* cum0  = dts1  + 8192;
    float* cum1  = cum0  + 8192;
    float* ssq0  = cum1  + 8192;
    float* ssq1  = ssq0  + 8192;
    float* partP = ssq1  + 8192;         // 2 slabs = 524288
    float* partO0= partP + 524288;       // 4 slabs = 1048576
    float* partO1= partO0+ 1048576;      // 4 slabs = 1048576
    float* f32end = partO1 + 1048576;

    ushort_t* wbuf = (ushort_t*)f32end;          // 1712128
    ushort_t* win_bf  = wbuf;                    // 4 x 296960
    ushort_t* wout_bf = wbuf + 1187840;          // 4 x 131072

    wconv_patch_k<<<1824, 256, 0, stream>>>(
        Win[0], Win[1], Wout[0], Wout[1], wbuf, x, patch_w, partP);

    float* partOs[2] = {partO0, partO1};
    for (int i = 0; i < DEPTH; ++i){
        const float* cw0  = cw[0]   + (size_t)i * CDIM * DCONV;
        const float* cw1  = cw[1]   + (size_t)i * CDIM * DCONV;
        const float* cb0  = cb[0]   + (size_t)i * CDIM;
        const float* cb1  = cb[1]   + (size_t)i * CDIM;
        const float* dtb0 = dtb[0]  + (size_t)i * H;
        const float* dtb1 = dtb[1]  + (size_t)i * H;
        const float* Al0  = Alog[0] + (size_t)i * H;
        const float* Al1  = Alog[1] + (size_t)i * H;
        const float* Dp0  = Dp[0]   + (size_t)i * H;
        const float* Dp1  = Dp[1]   + (size_t)i * H;
        const float* gn0  = gn[0]   + (size_t)i * DIN;
        const float* gn1  = gn[1]   + (size_t)i * DIN;
        const ushort_t* Wi0 = win_bf  + (size_t)(2 * i + 0) * 296960;
        const ushort_t* Wi1 = win_bf  + (size_t)(2 * i + 1) * 296960;
        const ushort_t* Wo0 = wout_bf + (size_t)(2 * i + 0) * 131072;
        const ushort_t* Wo1 = wout_bf + (size_t)(2 * i + 1) * 131072;
        const float* pO = (i == 0) ? nullptr : partO0;

        gemm_in_k<<<dim3(19, 16, 2), 256, 0, stream>>>(
            partP, patch_b, pos, pO, norms_w + i * D, Wi0, Wi1,
            cw0, cw1, cb0, cb1, dtb0, dtb1, Al0, Al1,
            zb0, zb1, xy0, xy1, bc0, bc1, dts0, dts1, cum0, cum1);
        yscan2_k<<<dim3(H, BATCH, 2), 512, 0, stream>>>(
            bc0, bc1, dts0, dts1, cum0, cum1, Dp0, Dp1, zb0, zb1,
            xy0, xy1, ssq0, ssq1);
        gemm_out_k<<<dim3(4, 16, 4), 256, 0, stream>>>(
            xy0, xy1, ssq0, ssq1, gn0, gn1, Wo0, Wo1, partOs[i]);
    }

    finalmean_k<<<dim3(BATCH, 8), 256, 0, stream>>>(
        partP, patch_b, pos, partO0, partO1, final_w, tm8);
    head_k<<<(BATCH * NCLS + 255) / 256, 256, 0, stream>>>(
        tm8, head_w, head_b, (float*)d_out);
}

// Round 14
// 129.178 us; speedup vs baseline: 3.8107x; 1.0883x over previous
//
#include <hip/hip_runtime.h>
#include <hip/hip_bf16.h>
#include <math.h>

#define IMG 128
#define PATCH 16
#define L 64
#define D 256
#define DIN 512
#define DH 64
#define H 8
#define NSTATE 64
#define DCONV 4
#define DEPTH 2
#define NCLS 1000
#define BATCH 16
#define DINPROJ 1160   // 2*DIN + 2*N + H
#define CDIM 640       // DIN + 2*N
#define EPS 1e-6f
#define SLAB (BATCH * L * D)   // 262144

typedef __attribute__((ext_vector_type(8))) short short8;
typedef __attribute__((ext_vector_type(4))) float f32x4;
typedef __attribute__((ext_vector_type(4))) unsigned short us4;
typedef unsigned short ushort_t;

__device__ __forceinline__ int snake_tok(int s){
    int r = s >> 3, c = s & 7;
    return (r & 1) ? (r * 8 + (7 - c)) : (r * 8 + c);
}
__device__ __forceinline__ float silu_f(float x){ return x / (1.f + expf(-x)); }
__device__ __forceinline__ float softplus_f(float x){ return x > 20.f ? x : log1pf(expf(x)); }
__device__ __forceinline__ ushort_t f2b(float f){
    __hip_bfloat16 h = __float2bfloat16(f);
    return *(ushort_t*)&h;
}

// ---------------- phase 0 (flattened, 2208 blocks): wconv (0..1695) + patch GEMM sK=8 (1696..2207)
__global__ __launch_bounds__(256) void wconv_patch_k(
    const float* __restrict__ Win0, const float* __restrict__ Win1,
    const float* __restrict__ Wout0, const float* __restrict__ Wout1,
    ushort_t* __restrict__ wbuf,
    const float* __restrict__ x, const float* __restrict__ PW,
    float* __restrict__ partP)
{
    __shared__ __align__(16) unsigned char SM[20480];
    const int task = blockIdx.x;
    const int tid = threadIdx.x;
    if (task < 1696){
        float (*sm)[33] = (float(*)[33])SM;
        const float* src; ushort_t* dst; int R, C, ctiles, tile;
        if (task < 1184){
            int z = task / 296; tile = task - z * 296;          // 37*8 tiles per z
            src = (z & 1 ? Win1 : Win0) + (size_t)(z >> 1) * D * DINPROJ;
            dst = wbuf + (size_t)z * 296960;
            R = D; C = DINPROJ; ctiles = 37;
        } else {
            int k = task - 1184;
            int z = k >> 7; tile = k & 127;                     // 8*16 tiles per z
            src = (z & 1 ? Wout1 : Wout0) + (size_t)(z >> 1) * DIN * D;
            dst = wbuf + 1187840 + (size_t)z * 131072;
            R = DIN; C = D; ctiles = 8;
        }
        int cx = tile % ctiles, ry = tile / ctiles;
        int c0 = cx * 32, r0 = ry * 32;
        int tx = tid & 31, ty = tid >> 5;
        #pragma unroll
        for (int k = 0; k < 4; ++k){
            int r = r0 + ty + 8 * k, c = c0 + tx;
            sm[ty + 8 * k][tx] = (c < C) ? src[(size_t)r * C + c] : 0.f;
        }
        __syncthreads();
        #pragma unroll
        for (int k = 0; k < 4; ++k){
            int dr = c0 + ty + 8 * k, dc = r0 + tx;
            if (dr < C) dst[(size_t)dr * R + dc] = f2b(sm[tx][ty + 8 * k]);
        }
        return;
    }
    // ---- patch GEMM: 512 tasks = xi(4) x b(16) x split(8), K=96 each ----
    ushort_t (*As)[64][40] = (ushort_t(*)[64][40])SM;
    ushort_t (*Bs)[64][40] = (ushort_t(*)[64][40])(SM + 10240);
    const int pt = task - 1696;
    const int xi = pt & 3, b = (pt >> 2) & 15, split = pt >> 6;
    const int n0 = xi * 64;
    const int kbase = split * 96;
    const int lrow = tid >> 2, lc8 = (tid & 3) * 8;
    const int tok = snake_tok(lrow), gy = tok >> 3, gx = tok & 7;
    const float* xb = x + (size_t)b * 3 * IMG * IMG;
    const int wave = tid >> 6, lane = tid & 63;
    const int wm = (wave >> 1) * 32, wn = (wave & 1) * 32;
    const int fro = lane & 15, fk = (lane >> 4) * 8;

    f32x4 acc[2][2];
    #pragma unroll
    for (int i = 0; i < 2; ++i)
        #pragma unroll
        for (int j = 0; j < 2; ++j) acc[i][j] = (f32x4){0.f,0.f,0.f,0.f};

    short8 areg, breg;
    auto gload = [&](int kk){
        int k = kk + lc8;
        int c = k >> 8, rem = k & 255, py = rem >> 4, px = rem & 15;
        const float* srcA = xb + ((size_t)c * IMG + gy * PATCH + py) * IMG + gx * PATCH + px;
        float4 a0 = *(const float4*)(srcA);
        float4 a1 = *(const float4*)(srcA + 4);
        ushort_t ta[8] = {f2b(a0.x),f2b(a0.y),f2b(a0.z),f2b(a0.w),
                          f2b(a1.x),f2b(a1.y),f2b(a1.z),f2b(a1.w)};
        areg = *(short8*)ta;
        const float* srcB = PW + (size_t)(n0 + lrow) * 768 + kk + lc8;
        float4 b0 = *(const float4*)(srcB);
        float4 b1 = *(const float4*)(srcB + 4);
        ushort_t tb[8] = {f2b(b0.x),f2b(b0.y),f2b(b0.z),f2b(b0.w),
                          f2b(b1.x),f2b(b1.y),f2b(b1.z),f2b(b1.w)};
        breg = *(short8*)tb;
    };
    auto sstore = [&](int buf){
        *(short8*)&As[buf][lrow][lc8] = areg;
        *(short8*)&Bs[buf][lrow][lc8] = breg;
    };

    const int nk = 3;
    gload(kbase); sstore(0);
    __syncthreads();
    for (int kt = 0; kt < nk; ++kt){
        const int buf = kt & 1;
        if (kt + 1 < nk) gload(kbase + (kt + 1) * 32);
        short8 af[2], bfr[2];
        af[0]  = *(const short8*)&As[buf][wm + fro][fk];
        af[1]  = *(const short8*)&As[buf][wm + 16 + fro][fk];
        bfr[0] = *(const short8*)&Bs[buf][wn + fro][fk];
        bfr[1] = *(const short8*)&Bs[buf][wn + 16 + fro][fk];
        #pragma unroll
        for (int i = 0; i < 2; ++i)
            #pragma unroll
            for (int j = 0; j < 2; ++j)
                acc[i][j] = __builtin_amdgcn_mfma_f32_16x16x32_bf16(af[i], bfr[j], acc[i][j], 0, 0, 0);
        if (kt + 1 < nk) sstore(buf ^ 1);
        __syncthreads();
    }
    float* Cp = partP + (size_t)split * SLAB;
    #pragma unroll
    for (int i = 0; i < 2; ++i){
        #pragma unroll
        for (int j = 0; j < 2; ++j){
            int col = n0 + wn + j * 16 + (lane & 15);
            #pragma unroll
            for (int r = 0; r < 4; ++r){
                int srow = wm + i * 16 + (lane >> 4) * 4 + r;
                Cp[(size_t)(b * 64 + srow) * D + col] = acc[i][j][r];
            }
        }
    }
}

// ---------------- patch reduce: t = sum(8 partials) + pb + pos
__global__ void patch_red_k(const float* __restrict__ part, const float* __restrict__ pb,
                            const float* __restrict__ pos, float* __restrict__ t){
    int i = blockIdx.x * 256 + threadIdx.x;
    int d = i & (D - 1), s = (i >> 8) & (L - 1);
    float v = 0.f;
    #pragma unroll
    for (int r = 0; r < 8; ++r) v += part[i + r * SLAB];
    t[i] = v + pb[d] + pos[snake_tok(s) * D + d];
}

// ---------------- in-proj GEMM + rmsnorm prologue + conv/dt epilogue. grid (19,16,2)
__global__ __launch_bounds__(256) void gemm_in_k(
    const float* __restrict__ T, const float* __restrict__ nw,
    const ushort_t* __restrict__ B0, const ushort_t* __restrict__ B1,
    const float* __restrict__ cw0, const float* __restrict__ cw1,
    const float* __restrict__ cb0, const float* __restrict__ cb1,
    const float* __restrict__ dtb0, const float* __restrict__ dtb1,
    const float* __restrict__ Al0, const float* __restrict__ Al1,
    float* __restrict__ zb0, float* __restrict__ zb1,
    float* __restrict__ xy0, float* __restrict__ xy1,
    float* __restrict__ bc0, float* __restrict__ bc1,
    float* __restrict__ dts0, float* __restrict__ dts1,
    float* __restrict__ cums0, float* __restrict__ cums1)
{
    __shared__ __align__(16) ushort_t As[64][264];
    __shared__ __align__(16) ushort_t Bs[2][64][40];
    __shared__ float Ctile[64][68];
    const int dir = blockIdx.z;
    const ushort_t* __restrict__ Bw = dir ? B1 : B0;
    const int tid = threadIdx.x;
    const int m0 = blockIdx.y * 64, n0 = blockIdx.x * 64;
    const int b = blockIdx.y;
    const int arow = tid >> 2;
    const int wave = tid >> 6, lane = tid & 63;
    const int wm = (wave >> 1) * 32, wn = (wave & 1) * 32;
    const int fro = lane & 15, fk = (lane >> 4) * 8;

    {   // rmsnorm prologue -> As bf16
        const float* src = T + (size_t)(m0 + arow) * D;
        float ss = 0.f;
        #pragma unroll
        for (int i = 0; i < 16; ++i){
            int c = (tid & 3) * 4 + i * 16;
            float4 v = *(const float4*)(src + c);
            ss += v.x*v.x + v.y*v.y + v.z*v.z + v.w*v.w;
        }
        ss += __shfl_xor(ss, 1);
        ss += __shfl_xor(ss, 2);
        float sc = rsqrtf(ss * (1.f / (float)D) + EPS);
        #pragma unroll
        for (int i = 0; i < 16; ++i){
            int c = (tid & 3) * 4 + i * 16;
            float4 v = *(const float4*)(src + c);
            float4 w = *(const float4*)(nw + c);
            us4 o = {f2b(v.x*sc*w.x), f2b(v.y*sc*w.y), f2b(v.z*sc*w.z), f2b(v.w*sc*w.w)};
            *(us4*)&As[arow][c] = o;
        }
    }
    const int lrow = tid >> 2, lc8 = (tid & 3) * 8;
    float4 breg;
    auto gloadB = [&](int kk){
        int gn = n0 + lrow;
        if (gn < DINPROJ) breg = *(const float4*)(Bw + (size_t)gn * D + kk + lc8);
        else breg = make_float4(0.f,0.f,0.f,0.f);
    };
    auto sstoreB = [&](int buf){ *(float4*)&Bs[buf][lrow][lc8] = breg; };

    f32x4 acc[2][2];
    #pragma unroll
    for (int i = 0; i < 2; ++i)
        #pragma unroll
        for (int j = 0; j < 2; ++j) acc[i][j] = (f32x4){0.f,0.f,0.f,0.f};

    gloadB(0); sstoreB(0);
    __syncthreads();
    const int nk = D / 32;
    for (int kt = 0; kt < nk; ++kt){
        const int buf = kt & 1;
        if (kt + 1 < nk) gloadB((kt + 1) * 32);
        short8 af[2], bfr[2];
        af[0]  = *(const short8*)&As[wm + fro][kt * 32 + fk];
        af[1]  = *(const short8*)&As[wm + 16 + fro][kt * 32 + fk];
        bfr[0] = *(const short8*)&Bs[buf][wn + fro][fk];
        bfr[1] = *(const short8*)&Bs[buf][wn + 16 + fro][fk];
        #pragma unroll
        for (int i = 0; i < 2; ++i)
            #pragma unroll
            for (int j = 0; j < 2; ++j)
                acc[i][j] = __builtin_amdgcn_mfma_f32_16x16x32_bf16(af[i], bfr[j], acc[i][j], 0, 0, 0);
        if (kt + 1 < nk) sstoreB(buf ^ 1);
        __syncthreads();
    }

    if (n0 < DIN){
        float* zb = dir ? zb1 : zb0;
        #pragma unroll
        for (int i = 0; i < 2; ++i){
            #pragma unroll
            for (int j = 0; j < 2; ++j){
                int col = n0 + wn + j * 16 + (lane & 15);
                #pragma unroll
                for (int r = 0; r < 4; ++r){
                    int row = m0 + wm + i * 16 + (lane >> 4) * 4 + r;
                    zb[(size_t)row * DIN + col] = acc[i][j][r];
                }
            }
        }
        return;
    }

    #pragma unroll
    for (int i = 0; i < 2; ++i){
        #pragma unroll
        for (int j = 0; j < 2; ++j){
            int lcol = wn + j * 16 + (lane & 15);
            #pragma unroll
            for (int r = 0; r < 4; ++r){
                int lr = wm + i * 16 + (lane >> 4) * 4 + r;
                Ctile[lr][lcol] = acc[i][j][r];
            }
        }
    }
    __syncthreads();

    if (blockIdx.x < 18){
        const float* cw = dir ? cw1 : cw0;
        const float* cb = dir ? cb1 : cb0;
        float* xy = dir ? xy1 : xy0;
        float* bc = dir ? bc1 : bc0;
        const int c = tid & 63;
        const int cc = n0 - DIN + c;
        const float w0 = cw[cc * DCONV + 0], w1 = cw[cc * DCONV + 1];
        const float w2 = cw[cc * DCONV + 2], w3 = cw[cc * DCONV + 3];
        const float bb = cb[cc];
        #pragma unroll
        for (int rep = 0; rep < 16; ++rep){
            int s = (tid >> 6) + rep * 4;
            float a = bb;
            {
                int sp = s - 3;
                if (sp >= 0) a += w0 * Ctile[dir ? 63 - sp : sp][c];
                sp = s - 2;
                if (sp >= 0) a += w1 * Ctile[dir ? 63 - sp : sp][c];
                sp = s - 1;
                if (sp >= 0) a += w2 * Ctile[dir ? 63 - sp : sp][c];
                a += w3 * Ctile[dir ? 63 - s : s][c];
            }
            float v = silu_f(a);
            if (cc < DIN) xy[(size_t)(b * 64 + s) * DIN + cc] = v;
            else          bc[(size_t)(b * 64 + s) * 128 + (cc - DIN)] = v;
        }
        return;
    }

    {   // dt block
        const float* dtb = dir ? dtb1 : dtb0;
        const float* Al  = dir ? Al1  : Al0;
        float* dts  = dir ? dts1  : dts0;
        float* cums = dir ? cums1 : cums0;
        int s = tid & 63;
        int l = dir ? (63 - s) : s;
        #pragma unroll
        for (int rep = 0; rep < 2; ++rep){
            int h = (tid >> 6) + rep * 4;
            float raw = Ctile[l][h] + dtb[h];
            float dt = softplus_f(raw);
            float val = -expf(Al[h]) * dt;
            #pragma unroll
            for (int o = 1; o < 64; o <<= 1){
                float u = __shfl_up(val, o);
                if (s >= o) val += u;
            }
            dts[(size_t)(b * 64 + s) * H + h]  = dt;
            cums[(size_t)(b * 64 + s) * H + h] = val;
        }
    }
}

// ---------------- S + mask + PV + gate + ssq, s-half split; grid (H, B, 4), 512 thr
// zz = dir*2 + half; writes g into gbuf (token order), ssq for owned rows.
__global__ __launch_bounds__(512) void yscan3_k(
    const float* __restrict__ bc0, const float* __restrict__ bc1,
    const float* __restrict__ dts0, const float* __restrict__ dts1,
    const float* __restrict__ cums0, const float* __restrict__ cums1,
    const float* __restrict__ Dp0, const float* __restrict__ Dp1,
    const float* __restrict__ zb0, const float* __restrict__ zb1,
    const float* __restrict__ xy0, const float* __restrict__ xy1,
    float* __restrict__ gb0, float* __restrict__ gb1,
    float* __restrict__ ssq0, float* __restrict__ ssq1)
{
    __shared__ float Bc[64][65];
    __shared__ float Xs[64][65];
    __shared__ float Cc[32][65];
    __shared__ float Am[32][65];
    __shared__ float cumS[64], dtS[64];
    __shared__ float ssqp[16][32];
    const int h = blockIdx.x, b = blockIdx.y;
    const int zz = blockIdx.z;
    const int dir = zz >> 1, half = zz & 1;
    const int s0 = half * 32;
    const float* bc   = dir ? bc1   : bc0;
    const float* dts  = dir ? dts1  : dts0;
    const float* cums = dir ? cums1 : cums0;
    const float* Dp   = dir ? Dp1   : Dp0;
    const float* zb   = dir ? zb1   : zb0;
    const float* xy   = dir ? xy1   : xy0;
    float* gb  = dir ? gb1  : gb0;
    float* ssq = dir ? ssq1 : ssq0;
    const int t = threadIdx.x;

    if (t < 64){
        cumS[t] = cums[(size_t)(b * L + t) * H + h];
        dtS[t]  = dts[(size_t)(b * L + t) * H + h];
    }
    for (int i = t; i < 4096; i += 512){
        int s = i >> 6, n = i & 63;
        Bc[s][n] = bc[(size_t)(b * L + s) * 128 + n];
        Xs[s][n] = xy[(size_t)(b * L + s) * DIN + h * DH + n];
    }
    for (int i = t; i < 2048; i += 512){
        int sl = i >> 6, n = i & 63;
        Cc[sl][n] = bc[(size_t)(b * L + s0 + sl) * 128 + 64 + n];
    }
    __syncthreads();
    for (int i = t; i < 2048; i += 512){
        int sl = i >> 6, j = i & 63;
        int s = s0 + sl;
        float v = 0.f;
        if (j <= s){
            float acc = 0.f;
            #pragma unroll
            for (int n = 0; n < 64; ++n) acc += Cc[sl][n] * Bc[j][n];
            v = acc * expf(cumS[s] - cumS[j]) * dtS[j];
        }
        Am[sl][j] = v;
    }
    __syncthreads();
    {   // PV + gate: thread -> (sl = t&31, pg = t>>5 covering 4 p's)
        const int sl = t & 31, pg = t >> 5;
        const int s = s0 + sl;
        const int l = dir ? (63 - s) : s;
        const size_t row = (size_t)(b * 64 + l);
        const float dp = Dp[h];
        float acc[4];
        #pragma unroll
        for (int pp = 0; pp < 4; ++pp) acc[pp] = dp * Xs[s][pg * 4 + pp];
        #pragma unroll
        for (int j = 0; j < 64; ++j){
            float am = Am[sl][j];
            #pragma unroll
            for (int pp = 0; pp < 4; ++pp)
                acc[pp] = fmaf(am, Xs[j][pg * 4 + pp], acc[pp]);
        }
        float4 z4 = *(const float4*)(zb + row * DIN + h * DH + pg * 4);
        float zv[4] = {z4.x, z4.y, z4.z, z4.w};
        float g2 = 0.f;
        float gout[4];
        #pragma unroll
        for (int pp = 0; pp < 4; ++pp){
            float g = acc[pp] * silu_f(zv[pp]);
            gout[pp] = g;
            g2 += g * g;
        }
        ssqp[pg][sl] = g2;
        *(float4*)(gb + row * DIN + h * DH + pg * 4) =
            make_float4(gout[0], gout[1], gout[2], gout[3]);
    }
    __syncthreads();
    if (t < 32){
        int s = s0 + t;
        int ll = dir ? (63 - s) : s;
        float v = 0.f;
        #pragma unroll
        for (int q = 0; q < 16; ++q) v += ssqp[q][t];
        ssq[(size_t)(b * 64 + ll) * H + h] = v;
    }
}

// ---------------- out-proj GEMM split-K=8 + gate-norm prologue; grid (4,16,8)
__global__ __launch_bounds__(256) void gemm_out_k(
    const float* __restrict__ G0, const float* __restrict__ G1,
    const float* __restrict__ ssq0, const float* __restrict__ ssq1,
    const float* __restrict__ gn0, const float* __restrict__ gn1,
    const ushort_t* __restrict__ B0, const ushort_t* __restrict__ B1,
    float* __restrict__ part)
{
    __shared__ __align__(16) ushort_t As[2][64][40];
    __shared__ __align__(16) ushort_t Bs[2][64][40];
    __shared__ float scl[64];
    const int tid = threadIdx.x;
    const int n0 = blockIdx.x * 64, m0 = blockIdx.y * 64;
    const int z = blockIdx.z;
    const int dir = z >> 2;
    const int kbase = (z & 3) * 128;
    const float* __restrict__ G   = dir ? G1   : G0;
    const float* __restrict__ ssq = dir ? ssq1 : ssq0;
    const float* __restrict__ gnw = dir ? gn1  : gn0;
    const ushort_t* __restrict__ B = dir ? B1 : B0;
    const int lrow = tid >> 2, lc8 = (tid & 3) * 8;
    const int wave = tid >> 6, lane = tid & 63;
    const int wm = (wave >> 1) * 32, wn = (wave & 1) * 32;
    const int fro = lane & 15, fk = (lane >> 4) * 8;

    if (tid < 64){
        const float* sr = ssq + (size_t)(m0 + tid) * H;
        float v = (sr[0] + sr[1]) + (sr[2] + sr[3]) + (sr[4] + sr[5]) + (sr[6] + sr[7]);
        scl[tid] = rsqrtf(v * (1.f / (float)DIN) + EPS);
    }
    __syncthreads();

    short8 areg; float4 breg;
    auto gload = [&](int kk){
        const float* src = G + (size_t)(m0 + lrow) * DIN + kk + lc8;
        float4 a0 = *(const float4*)(src);
        float4 a1 = *(const float4*)(src + 4);
        const float* gw = gnw + kk + lc8;
        float4 w0 = *(const float4*)(gw);
        float4 w1 = *(const float4*)(gw + 4);
        float sc = scl[lrow];
        ushort_t ta[8] = {f2b(a0.x*sc*w0.x), f2b(a0.y*sc*w0.y), f2b(a0.z*sc*w0.z), f2b(a0.w*sc*w0.w),
                          f2b(a1.x*sc*w1.x), f2b(a1.y*sc*w1.y), f2b(a1.z*sc*w1.z), f2b(a1.w*sc*w1.w)};
        areg = *(short8*)ta;
        breg = *(const float4*)(B + (size_t)(n0 + lrow) * DIN + kk + lc8);
    };
    auto sstore = [&](int buf){
        *(short8*)&As[buf][lrow][lc8] = areg;
        *(float4*)&Bs[buf][lrow][lc8] = breg;
    };

    f32x4 acc[2][2];
    #pragma unroll
    for (int i = 0; i < 2; ++i)
        #pragma unroll
        for (int j = 0; j < 2; ++j) acc[i][j] = (f32x4){0.f,0.f,0.f,0.f};

    const int nk = 4;
    gload(kbase); sstore(0);
    __syncthreads();
    for (int kt = 0; kt < nk; ++kt){
        const int buf = kt & 1;
        if (kt + 1 < nk) gload(kbase + (kt + 1) * 32);
        short8 af[2], bfr[2];
        af[0]  = *(const short8*)&As[buf][wm + fro][fk];
        af[1]  = *(const short8*)&As[buf][wm + 16 + fro][fk];
        bfr[0] = *(const short8*)&Bs[buf][wn + fro][fk];
        bfr[1] = *(const short8*)&Bs[buf][wn + 16 + fro][fk];
        #pragma unroll
        for (int i = 0; i < 2; ++i)
            #pragma unroll
            for (int j = 0; j < 2; ++j)
                acc[i][j] = __builtin_amdgcn_mfma_f32_16x16x32_bf16(af[i], bfr[j], acc[i][j], 0, 0, 0);
        if (kt + 1 < nk) sstore(buf ^ 1);
        __syncthreads();
    }
    float* Cp = part + (size_t)z * SLAB;
    #pragma unroll
    for (int i = 0; i < 2; ++i){
        #pragma unroll
        for (int j = 0; j < 2; ++j){
            int col = n0 + wn + j * 16 + (lane & 15);
            #pragma unroll
            for (int r = 0; r < 4; ++r){
                int row = m0 + wm + i * 16 + (lane >> 4) * 4 + r;
                Cp[(size_t)row * D + col] = acc[i][j][r];
            }
        }
    }
}

// ---------------- out reduce (layer 0 only): t += 0.5 * sum(8 partials)
__global__ void out_red_k(const float* __restrict__ part, float* __restrict__ t){
    int i = blockIdx.x * 256 + threadIdx.x;
    float v = 0.f;
    #pragma unroll
    for (int r = 0; r < 8; ++r) v += part[i + r * SLAB];
    t[i] += 0.5f * v;
}

// ---------------- final: teff = t + 0.5*sum(part), rmsnorm rows, partial mean
__global__ void finalmean_k(const float* __restrict__ T, const float* __restrict__ part,
                            const float* __restrict__ fw, float* __restrict__ tm8){
    __shared__ float sm4[4];
    int b = blockIdx.x, q = blockIdx.y;
    int d = threadIdx.x;
    float a = 0.f;
    for (int r = 0; r < 8; ++r){
        int row = b * 64 + q * 8 + r;
        size_t o = (size_t)row * D + d;
        float pv = 0.f;
        #pragma unroll
        for (int u = 0; u < 8; ++u) pv += part[o + (size_t)u * SLAB];
        float v = T[o] + 0.5f * pv;
        float ssl = v * v;
        #pragma unroll
        for (int off = 32; off > 0; off >>= 1) ssl += __shfl_down(ssl, off);
        if ((threadIdx.x & 63) == 0) sm4[threadIdx.x >> 6] = ssl;
        __syncthreads();
        float ss = sm4[0] + sm4[1] + sm4[2] + sm4[3];
        __syncthreads();
        float sc = rsqrtf(ss / (float)D + EPS);
        a += v * sc;
    }
    tm8[(q * BATCH + b) * D + d] = a * (1.f / (float)L) * fw[d];
}

// ---------------- head: single kernel, K=256, tm8 slabs summed in LDS, +bias
__global__ void head_k(const float* __restrict__ tm8, const float* __restrict__ hw,
                       const float* __restrict__ hb, float* __restrict__ out){
    __shared__ float trs[2][256];
    int i0 = blockIdx.x * 256;
    int mmin = i0 / NCLS;
    int t = threadIdx.x;
    #pragma unroll
    for (int mm = 0; mm < 2; ++mm){
        int m = mmin + mm;
        float v = 0.f;
        if (m < BATCH){
            #pragma unroll
            for (int q = 0; q < 8; ++q)
                v += tm8[(q * BATCH + m) * D + t];
        }
        trs[mm][t] = v;
    }
    __syncthreads();
    int i = i0 + t;
    if (i >= BATCH * NCLS) return;
    int m = i / NCLS, n = i - m * NCLS;
    const float* tr = trs[m - mmin];
    const float* hc = hw + n;
    float a0 = 0.f, a1 = 0.f, a2 = 0.f, a3 = 0.f;
    #pragma unroll 4
    for (int k = 0; k < D; k += 4){
        a0 = fmaf(tr[k],     hc[(size_t)k * NCLS],       a0);
        a1 = fmaf(tr[k + 1], hc[(size_t)(k + 1) * NCLS], a1);
        a2 = fmaf(tr[k + 2], hc[(size_t)(k + 2) * NCLS], a2);
        a3 = fmaf(tr[k + 3], hc[(size_t)(k + 3) * NCLS], a3);
    }
    out[i] = (a0 + a1) + (a2 + a3) + hb[n];
}

extern "C" void kernel_launch(void* const* d_in, const int* in_sizes, int n_in,
                              void* d_out, int out_size, void* d_ws, size_t ws_size,
                              hipStream_t stream){
    (void)in_sizes; (void)n_in; (void)out_size; (void)ws_size;
    const float* x       = (const float*)d_in[0];
    const float* patch_w = (const float*)d_in[1];
    const float* patch_b = (const float*)d_in[2];
    const float* pos     = (const float*)d_in[3];
    const float* norms_w = (const float*)d_in[4];
    const float* final_w = (const float*)d_in[5];
    const float* head_w  = (const float*)d_in[6];
    const float* head_b  = (const float*)d_in[7];
    const float* Win[2]  = {(const float*)d_in[8],  (const float*)d_in[16]};
    const float* cw[2]   = {(const float*)d_in[9],  (const float*)d_in[17]};
    const float* cb[2]   = {(const float*)d_in[10], (const float*)d_in[18]};
    const float* dtb[2]  = {(const float*)d_in[11], (const float*)d_in[19]};
    const float* Alog[2] = {(const float*)d_in[12], (const float*)d_in[20]};
    const float* Dp[2]   = {(const float*)d_in[13], (const float*)d_in[21]};
    const float* gn[2]   = {(const float*)d_in[14], (const float*)d_in[22]};
    const float* Wout[2] = {(const float*)d_in[15], (const float*)d_in[23]};

    float* ws = (float*)d_ws;
    float* t     = ws;                   // 262144
    float* tm8   = t     + 262144;       // 32768
    float* zb0   = tm8   + 32768;        // 524288
    float* zb1   = zb0   + 524288;
    float* xy0   = zb1   + 524288;       // 524288 (xs)
    float* xy1   = xy0   + 524288;
    float* gb0   = xy1   + 524288;       // 524288 (gate output)
    float* gb1   = gb0   + 524288;
    float* bc0   = gb1   + 524288;       // 131072
    float* bc1   = bc0   + 131072;
    float* dts0  = bc1   + 131072;       // 8192 x6
    float* dts1  = dts0  + 8192;
    float* cum0  = dts1  + 8192;
    float* cum1  = cum0  + 8192;
    float* ssq0  = cum1  + 8192;
    float* ssq1  = ssq0  + 8192;
    float* partP = ssq1  + 8192;         // 2097152
    float* partO = partP + 2097152;      // 2097152
    float* f32end = partO + 2097152;

    ushort_t* wbuf = (ushort_t*)f32end;          // 1712128
    ushort_t* win_bf  = wbuf;                    // 4 x 296960
    ushort_t* wout_bf = wbuf + 1187840;          // 4 x 131072

    const int BL = BATCH * L;   // 1024

    wconv_patch_k<<<2208, 256, 0, stream>>>(
        Win[0], Win[1], Wout[0], Wout[1], wbuf, x, patch_w, partP);
    patch_red_k<<<BL, 256, 0, stream>>>(partP, patch_b, pos, t);

    for (int i = 0; i < DEPTH; ++i){
        const float* cw0  = cw[0]   + (size_t)i * CDIM * DCONV;
        const float* cw1  = cw[1]   + (size_t)i * CDIM * DCONV;
        const float* cb0  = cb[0]   + (size_t)i * CDIM;
        const float* cb1  = cb[1]   + (size_t)i * CDIM;
        const float* dtb0 = dtb[0]  + (size_t)i * H;
        const float* dtb1 = dtb[1]  + (size_t)i * H;
        const float* Al0  = Alog[0] + (size_t)i * H;
        const float* Al1  = Alog[1] + (size_t)i * H;
        const float* Dp0  = Dp[0]   + (size_t)i * H;
        const float* Dp1  = Dp[1]   + (size_t)i * H;
        const float* gn0  = gn[0]   + (size_t)i * DIN;
        const float* gn1  = gn[1]   + (size_t)i * DIN;
        const ushort_t* Wi0 = win_bf  + (size_t)(2 * i + 0) * 296960;
        const ushort_t* Wi1 = win_bf  + (size_t)(2 * i + 1) * 296960;
        const ushort_t* Wo0 = wout_bf + (size_t)(2 * i + 0) * 131072;
        const ushort_t* Wo1 = wout_bf + (size_t)(2 * i + 1) * 131072;

        gemm_in_k<<<dim3(19, 16, 2), 256, 0, stream>>>(
            t, norms_w + i * D, Wi0, Wi1, cw0, cw1, cb0, cb1, dtb0, dtb1,
            Al0, Al1, zb0, zb1, xy0, xy1, bc0, bc1, dts0, dts1, cum0, cum1);
        yscan3_k<<<dim3(H, BATCH, 4), 512, 0, stream>>>(
            bc0, bc1, dts0, dts1, cum0, cum1, Dp0, Dp1, zb0, zb1,
            xy0, xy1, gb0, gb1, ssq0, ssq1);
        gemm_out_k<<<dim3(4, 16, 8), 256, 0, stream>>>(
            gb0, gb1, ssq0, ssq1, gn0, gn1, Wo0, Wo1, partO);
        if (i == 0)
            out_red_k<<<BL, 256, 0, stream>>>(partO, t);
    }

    finalmean_k<<<dim3(BATCH, 8), 256, 0, stream>>>(t, partO, final_w, tm8);
    head_k<<<(BATCH * NCLS + 255) / 256, 256, 0, stream>>>(
        tm8, head_w, head_b, (float*)d_out);
}